// Round 2
// baseline (619.628 us; speedup 1.0000x reference)
//
#include <hip/hip_runtime.h>

#define NN 50000
#define NE 800000
#define D  64
#define NL 2
#define NB 196   // (NN + 255) / 256

typedef __bf16 bf16x8 __attribute__((ext_vector_type(8)));
typedef float  floatx4 __attribute__((ext_vector_type(4)));

static __device__ __forceinline__ float bf2f(unsigned short u) {
    return __uint_as_float(((unsigned)u) << 16);
}
static __device__ __forceinline__ unsigned short f2bf(float x) {
    unsigned u = __float_as_uint(x);
    u += 0x7fff + ((u >> 16) & 1);   // RNE
    return (unsigned short)(u >> 16);
}

// ---------------- CSR build (edge_index is identical for both layers) ----------------

__global__ void k_deg(const int* __restrict__ ei, int* __restrict__ deg) {
    int e = blockIdx.x * 256 + threadIdx.x;
    if (e < NE) atomicAdd(&deg[ei[NE + e]], 1);
}

// phase 1: per-block sums of deg
__global__ __launch_bounds__(256) void k_scan1(const int* __restrict__ deg,
                                               int* __restrict__ psum) {
    __shared__ int red[4];
    int i = blockIdx.x * 256 + threadIdx.x;
    int v = (i < NN) ? deg[i] : 0;
#pragma unroll
    for (int m = 1; m < 64; m <<= 1) v += __shfl_xor(v, m, 64);
    if ((threadIdx.x & 63) == 0) red[threadIdx.x >> 6] = v;
    __syncthreads();
    if (threadIdx.x == 0) psum[blockIdx.x] = red[0] + red[1] + red[2] + red[3];
}

// phase 2: exclusive scan of the NB partial sums (single small block)
__global__ void k_scan2(int* __restrict__ psum) {
    __shared__ int buf[256];
    int t = threadIdx.x;
    int v = (t < NB) ? psum[t] : 0;
    buf[t] = v;
    __syncthreads();
    for (int o = 1; o < 256; o <<= 1) {
        int x = (t >= o) ? buf[t - o] : 0;
        __syncthreads();
        buf[t] += x;
        __syncthreads();
    }
    if (t < NB) psum[t] = buf[t] - v;   // exclusive
}

// phase 3: block-local scan + block offset -> row_off / cursor
__global__ __launch_bounds__(256) void k_scan3(const int* __restrict__ deg,
                                               const int* __restrict__ psum,
                                               int* __restrict__ row_off,
                                               int* __restrict__ cursor) {
    __shared__ int buf[256];
    int t = threadIdx.x;
    int i = blockIdx.x * 256 + t;
    int v = (i < NN) ? deg[i] : 0;
    buf[t] = v;
    __syncthreads();
    for (int o = 1; o < 256; o <<= 1) {
        int x = (t >= o) ? buf[t - o] : 0;
        __syncthreads();
        buf[t] += x;
        __syncthreads();
    }
    if (i < NN) {
        int inc = buf[t] + psum[blockIdx.x];   // global inclusive prefix through i
        row_off[i + 1] = inc;
        cursor[i] = inc - v;                   // exclusive
        if (i == 0) row_off[0] = 0;
    }
}

// csr_src[pos]=src ; csr_dst[pos]=dst ; eperm[e]=pos
__global__ void k_scatter(const int* __restrict__ ei, int* __restrict__ cursor,
                          int* __restrict__ csr_src, int* __restrict__ csr_dst,
                          int* __restrict__ eperm) {
    int e = blockIdx.x * 256 + threadIdx.x;
    if (e < NE) {
        int dst = ei[NE + e];
        int pos = atomicAdd(&cursor[dst], 1);
        csr_src[pos] = ei[e];
        csr_dst[pos] = dst;
        eperm[e] = pos;
    }
}

// transpose all weights to bf16 m-major [m][k] once per call.
__global__ __launch_bounds__(256) void k_prep(
        const float* __restrict__ WQ, const float* __restrict__ WK,
        const float* __restrict__ WV, const float* __restrict__ WE,
        const float* __restrict__ WO, const float* __restrict__ W1,
        const float* __restrict__ W2,
        unsigned short* __restrict__ wqT, unsigned short* __restrict__ wkT,
        unsigned short* __restrict__ wvT, unsigned short* __restrict__ weT,
        unsigned short* __restrict__ woT, unsigned short* __restrict__ w1T,
        unsigned short* __restrict__ w2T) {
    int idx = blockIdx.x * 256 + threadIdx.x;
    if (idx >= 2 * 36864) return;
    int l = idx / 36864;
    int r = idx % 36864;
    if (r < 20480) {                       // five 64x64 matrices
        int which = r >> 12, rr = r & 4095;
        int m = rr >> 6, k = rr & 63;
        const float* src = (which == 0 ? WQ : which == 1 ? WK : which == 2 ? WV :
                            which == 3 ? WE : WO);
        unsigned short* dst = (which == 0 ? wqT : which == 1 ? wkT : which == 2 ? wvT :
                               which == 3 ? weT : woT);
        dst[l * 4096 + rr] = f2bf(src[l * 4096 + k * 64 + m]);
    } else if (r < 28672) {                // W1: [64k][128m] -> w1T[m][k]
        int r2 = r - 20480;
        int m = r2 >> 6, k = r2 & 63;
        w1T[l * 8192 + r2] = f2bf(W1[l * 8192 + k * 128 + m]);
    } else {                               // W2: [128k][64m] -> w2T[m][k]
        int r3 = r - 28672;
        int m = r3 >> 7, k = r3 & 127;
        w2T[l * 8192 + r3] = f2bf(W2[l * 8192 + k * 64 + m]);
    }
}

// ---------------- kernels ----------------

// QKV via MFMA: one 16-node tile per wave. Q fp32 direct stores, K/V bf16 via LDS.
__global__ __launch_bounds__(256) void k_qkv_mfma(const float* __restrict__ h,
        const unsigned short* __restrict__ wqT, const unsigned short* __restrict__ wkT,
        const unsigned short* __restrict__ wvT,
        float* __restrict__ Qh, unsigned short* __restrict__ Kb,
        unsigned short* __restrict__ Vb) {
    __shared__ unsigned short st[4][16 * 72];
    const int lane = threadIdx.x & 63;
    const int w    = threadIdx.x >> 6;
    const int ml   = lane & 15;
    const int quad = lane >> 4;

    bf16x8 aq[2][4], ak[2][4], av[2][4];
#pragma unroll
    for (int kt = 0; kt < 2; kt++)
#pragma unroll
        for (int mt = 0; mt < 4; mt++) {
            int o = (mt*16 + ml)*64 + kt*32 + quad*8;
            aq[kt][mt] = *(const bf16x8*)&wqT[o];
            ak[kt][mt] = *(const bf16x8*)&wkT[o];
            av[kt][mt] = *(const bf16x8*)&wvT[o];
        }

    const int wave = blockIdx.x * 4 + w;
    const int nw   = gridDim.x * 4;
    for (int tile = wave; tile < NN / 16; tile += nw) {
        const int e0 = tile * 16;
        const float4* ar = (const float4*)(h + (size_t)(e0 + ml) * D);
        bf16x8 b[2];
#pragma unroll
        for (int kt = 0; kt < 2; kt++) {
            float4 f0 = ar[kt*8 + quad*2 + 0];
            float4 f1 = ar[kt*8 + quad*2 + 1];
            b[kt][0] = (__bf16)f0.x; b[kt][1] = (__bf16)f0.y;
            b[kt][2] = (__bf16)f0.z; b[kt][3] = (__bf16)f0.w;
            b[kt][4] = (__bf16)f1.x; b[kt][5] = (__bf16)f1.y;
            b[kt][6] = (__bf16)f1.z; b[kt][7] = (__bf16)f1.w;
        }
        floatx4 accq[4] = {}, acck[4] = {}, accv[4] = {};
#pragma unroll
        for (int kt = 0; kt < 2; kt++)
#pragma unroll
            for (int mt = 0; mt < 4; mt++) {
                accq[mt] = __builtin_amdgcn_mfma_f32_16x16x32_bf16(aq[kt][mt], b[kt], accq[mt], 0, 0, 0);
                acck[mt] = __builtin_amdgcn_mfma_f32_16x16x32_bf16(ak[kt][mt], b[kt], acck[mt], 0, 0, 0);
                accv[mt] = __builtin_amdgcn_mfma_f32_16x16x32_bf16(av[kt][mt], b[kt], accv[mt], 0, 0, 0);
            }
#pragma unroll
        for (int mt = 0; mt < 4; mt++)
            *(float4*)(Qh + (size_t)(e0 + ml) * D + mt*16 + quad*4) =
                make_float4(accq[mt][0], accq[mt][1], accq[mt][2], accq[mt][3]);
        const int el = lane >> 2, c = lane & 3;
#pragma unroll
        for (int mt = 0; mt < 4; mt++)
            *(ushort4*)&st[w][ml*72 + mt*16 + quad*4] =
                make_ushort4(f2bf(acck[mt][0]), f2bf(acck[mt][1]),
                             f2bf(acck[mt][2]), f2bf(acck[mt][3]));
        {
            uint4 r0 = *(const uint4*)&st[w][el*72 + c*16 + 0];
            uint4 r1 = *(const uint4*)&st[w][el*72 + c*16 + 8];
            uint4* gp = (uint4*)(Kb + (size_t)(e0 + el) * D + c*16);
            gp[0] = r0; gp[1] = r1;
        }
#pragma unroll
        for (int mt = 0; mt < 4; mt++)
            *(ushort4*)&st[w][ml*72 + mt*16 + quad*4] =
                make_ushort4(f2bf(accv[mt][0]), f2bf(accv[mt][1]),
                             f2bf(accv[mt][2]), f2bf(accv[mt][3]));
        {
            uint4 r0 = *(const uint4*)&st[w][el*72 + c*16 + 0];
            uint4 r1 = *(const uint4*)&st[w][el*72 + c*16 + 8];
            uint4* gp = (uint4*)(Vb + (size_t)(e0 + el) * D + c*16);
            gp[0] = r0; gp[1] = r1;
        }
    }
}

// Eh pass: computes layer-0 SCORES in-register (Eh0 never hits memory) and
// materializes Eh1 (CSR order) for the layer-1 score kernel.
// MFMA C-layout: acc[mt][r] = E value of edge (e0+ml) at dim mt*16+quad*4+r.
__global__ __launch_bounds__(256) void k_eh_score(const float* __restrict__ ea,
        const unsigned short* __restrict__ weT, const int* __restrict__ eperm,
        const int* __restrict__ ei, const float* __restrict__ Qh,
        const unsigned short* __restrict__ Kb,
        float* __restrict__ scb, unsigned short* __restrict__ Eh1) {
    __shared__ unsigned short st[4][16 * 72];
    const int lane = threadIdx.x & 63;
    const int w    = threadIdx.x >> 6;
    const int ml   = lane & 15;
    const int quad = lane >> 4;

    bf16x8 afr[2][2][4];   // [layer][kt][mt]
#pragma unroll
    for (int l = 0; l < 2; l++)
#pragma unroll
        for (int kt = 0; kt < 2; kt++)
#pragma unroll
            for (int mt = 0; mt < 4; mt++)
                afr[l][kt][mt] = *(const bf16x8*)&weT[l*4096 + (mt*16 + ml)*64 + kt*32 + quad*8];

    const int wave = blockIdx.x * 4 + w;
    const int nw   = gridDim.x * 4;
    const int el = lane >> 2, c = lane & 3;
    for (int tile = wave; tile < NE / 16; tile += nw) {
        const int e0 = tile * 16;
        const float4* ar = (const float4*)(ea + (size_t)(e0 + ml) * D);
        bf16x8 b[2];
#pragma unroll
        for (int kt = 0; kt < 2; kt++) {
            float4 f0 = ar[kt*8 + quad*2 + 0];
            float4 f1 = ar[kt*8 + quad*2 + 1];
            b[kt][0] = (__bf16)f0.x; b[kt][1] = (__bf16)f0.y;
            b[kt][2] = (__bf16)f0.z; b[kt][3] = (__bf16)f0.w;
            b[kt][4] = (__bf16)f1.x; b[kt][5] = (__bf16)f1.y;
            b[kt][6] = (__bf16)f1.z; b[kt][7] = (__bf16)f1.w;
        }
        const int eid  = e0 + ml;
        const int srcn = ei[eid];
        const int dstn = ei[NE + eid];
        const int posm = eperm[eid];
        const int pose = eperm[e0 + el];

        // ---- layer 0: per-head scores, no Eh0 materialization
        {
            floatx4 acc[4] = {};
#pragma unroll
            for (int kt = 0; kt < 2; kt++)
#pragma unroll
                for (int mt = 0; mt < 4; mt++)
                    acc[mt] = __builtin_amdgcn_mfma_f32_16x16x32_bf16(afr[0][kt][mt], b[kt], acc[mt], 0, 0, 0);
            float scq[4];
#pragma unroll
            for (int mt = 0; mt < 4; mt++) {
                float4 q4 = *(const float4*)(Qh + (size_t)dstn * D + mt*16 + quad*4);
                ushort4 k4 = *(const ushort4*)(Kb + (size_t)srcn * D + mt*16 + quad*4);
                float p = acc[mt][0] * q4.x * bf2f(k4.x)
                        + acc[mt][1] * q4.y * bf2f(k4.y)
                        + acc[mt][2] * q4.z * bf2f(k4.z)
                        + acc[mt][3] * q4.w * bf2f(k4.w);
                p += __shfl_xor(p, 16, 64);
                p += __shfl_xor(p, 32, 64);
                scq[mt] = __expf(fminf(5.f, fmaxf(-5.f, p * 0.25f)));
            }
            if (quad == 0)
                *(float4*)(scb + (size_t)posm * 4) =
                    make_float4(scq[0], scq[1], scq[2], scq[3]);
        }
        // ---- layer 1: materialize Eh1 (CSR order)
        {
            floatx4 acc[4] = {};
#pragma unroll
            for (int kt = 0; kt < 2; kt++)
#pragma unroll
                for (int mt = 0; mt < 4; mt++)
                    acc[mt] = __builtin_amdgcn_mfma_f32_16x16x32_bf16(afr[1][kt][mt], b[kt], acc[mt], 0, 0, 0);
#pragma unroll
            for (int mt = 0; mt < 4; mt++)
                *(ushort4*)&st[w][ml*72 + mt*16 + quad*4] =
                    make_ushort4(f2bf(acc[mt][0]), f2bf(acc[mt][1]),
                                 f2bf(acc[mt][2]), f2bf(acc[mt][3]));
            uint4 r0 = *(const uint4*)&st[w][el*72 + c*16 + 0];
            uint4 r1 = *(const uint4*)&st[w][el*72 + c*16 + 8];
            uint4* gp = (uint4*)(Eh1 + (size_t)pose * D + c*16);
            gp[0] = r0;
            gp[1] = r1;
        }
    }
}

// layer-1 edge scores: edge-parallel, lane = (edge ml, head quad), 16 dims in-lane,
// zero shuffles. Eh1 coalesced, dst near-sorted (CSR), K gathered (L2/L3-hot).
__global__ __launch_bounds__(256) void k_score1(
        const unsigned short* __restrict__ Eh1,
        const float* __restrict__ Qh, const unsigned short* __restrict__ Kb,
        const int* __restrict__ csr_src, const int* __restrict__ csr_dst,
        float* __restrict__ scb) {
    const int lane = threadIdx.x & 63;
    const int w    = threadIdx.x >> 6;
    const int ml   = lane & 15;
    const int quad = lane >> 4;      // head index
    const int wave = blockIdx.x * 4 + w;
    const int nw   = gridDim.x * 4;
    for (int tile = wave; tile < NE / 16; tile += nw) {
        const int p = tile * 16 + ml;
        const int src = csr_src[p];
        const int dst = csr_dst[p];
        bf16x8 e0v = *(const bf16x8*)(Eh1 + (size_t)p * D + quad*16);
        bf16x8 e1v = *(const bf16x8*)(Eh1 + (size_t)p * D + quad*16 + 8);
        bf16x8 k0v = *(const bf16x8*)(Kb + (size_t)src * D + quad*16);
        bf16x8 k1v = *(const bf16x8*)(Kb + (size_t)src * D + quad*16 + 8);
        const float4* qp = (const float4*)(Qh + (size_t)dst * D + quad*16);
        float4 q0 = qp[0], q1 = qp[1], q2 = qp[2], q3 = qp[3];
        float s = (float)e0v[0] * q0.x * (float)k0v[0]
                + (float)e0v[1] * q0.y * (float)k0v[1]
                + (float)e0v[2] * q0.z * (float)k0v[2]
                + (float)e0v[3] * q0.w * (float)k0v[3]
                + (float)e0v[4] * q1.x * (float)k0v[4]
                + (float)e0v[5] * q1.y * (float)k0v[5]
                + (float)e0v[6] * q1.z * (float)k0v[6]
                + (float)e0v[7] * q1.w * (float)k0v[7]
                + (float)e1v[0] * q2.x * (float)k1v[0]
                + (float)e1v[1] * q2.y * (float)k1v[1]
                + (float)e1v[2] * q2.z * (float)k1v[2]
                + (float)e1v[3] * q2.w * (float)k1v[3]
                + (float)e1v[4] * q3.x * (float)k1v[4]
                + (float)e1v[5] * q3.y * (float)k1v[5]
                + (float)e1v[6] * q3.z * (float)k1v[6]
                + (float)e1v[7] * q3.w * (float)k1v[7];
        scb[(size_t)p * 4 + quad] = __expf(fminf(5.f, fmaxf(-5.f, s * 0.25f)));
    }
}

// attention aggregation: one wave per node; only score read + V gather per edge.
__global__ __launch_bounds__(256) void k_agg(
        const unsigned short* __restrict__ Vb, const float* __restrict__ scb,
        const int* __restrict__ row_off, const int* __restrict__ csr_src,
        float* __restrict__ h_attn) {
    const int node = blockIdx.x * 4 + (threadIdx.x >> 6);
    if (node >= NN) return;
    const int lane  = threadIdx.x & 63;
    const int eslot = lane >> 4;
    const int ml    = lane & 15;
    const int hsel  = ml >> 2;     // head of this lane
    const int beg = row_off[node], end = row_off[node + 1];
    float4 acc = make_float4(0.f, 0.f, 0.f, 0.f);
    float z = 0.f;

    for (int cbeg = beg; cbeg < end; cbeg += 64) {
        const int cnt = min(64, end - cbeg);
        int myidx = cbeg + lane;
        int mysrc = (myidx < end) ? csr_src[myidx] : 0;

        for (int base = 0; base < cnt; base += 16) {
            int  jj[4];
            int  s[4];
            bool act[4];
#pragma unroll
            for (int u = 0; u < 4; u++) {
                int j = base + eslot + 4 * u;
                act[u] = j < cnt;
                jj[u]  = act[u] ? j : 0;
                s[u]   = __shfl(mysrc, jj[u], 64);
            }
            ushort4 vb[4];
            float   sv[4];
#pragma unroll
            for (int u = 0; u < 4; u++) {
                vb[u] = *(const ushort4*)(Vb + (size_t)s[u] * D + ml * 4);
                sv[u] = scb[(size_t)(cbeg + jj[u]) * 4 + hsel];
            }
#pragma unroll
            for (int u = 0; u < 4; u++) {
                float sc = act[u] ? sv[u] : 0.f;
                acc.x += sc * bf2f(vb[u].x);
                acc.y += sc * bf2f(vb[u].y);
                acc.z += sc * bf2f(vb[u].z);
                acc.w += sc * bf2f(vb[u].w);
                z += sc;
            }
        }
    }
    // merge the 4 edge-slots (butterfly over the eslot bits)
#pragma unroll
    for (int m = 16; m <= 32; m <<= 1) {
        acc.x += __shfl_xor(acc.x, m, 64);
        acc.y += __shfl_xor(acc.y, m, 64);
        acc.z += __shfl_xor(acc.z, m, 64);
        acc.w += __shfl_xor(acc.w, m, 64);
        z     += __shfl_xor(z, m, 64);
    }
    if (eslot == 0) {
        float inv = 1.f / (z + 1e-6f);
        ((float4*)(h_attn + (size_t)node * D))[ml] =
            make_float4(acc.x * inv, acc.y * inv, acc.z * inv, acc.w * inv);
    }
}

// MFMA-based fused post block: one 16-node tile per wave.
__global__ __launch_bounds__(512) void k_post_mfma(const float* __restrict__ h_in,
        const float* __restrict__ h_attn,
        const unsigned short* __restrict__ woT_g,
        const unsigned short* __restrict__ w1T_g,
        const unsigned short* __restrict__ w2T_g,
        const float* __restrict__ bo,
        const float* __restrict__ g1, const float* __restrict__ be1,
        const float* __restrict__ b1, const float* __restrict__ b2,
        const float* __restrict__ g2, const float* __restrict__ be2,
        float* __restrict__ h_out) {
    __shared__ unsigned short woT_s[64 * 72];
    __shared__ unsigned short w1T_s[128 * 72];
    __shared__ unsigned short w2T_s[64 * 136];
    __shared__ unsigned short stg[8][16 * 136];

    const int t = threadIdx.x;
    {
        const uint4* s0 = (const uint4*)woT_g;
        { int i = t; if (i < 512) { int row = i >> 3, c = i & 7;
              *(uint4*)&woT_s[row*72 + c*8] = s0[i]; } }
        const uint4* s1 = (const uint4*)w1T_g;
        for (int i = t; i < 1024; i += 512) {
            int row = i >> 3, c = i & 7;
            *(uint4*)&w1T_s[row*72 + c*8] = s1[i];
        }
        const uint4* s2 = (const uint4*)w2T_g;
        for (int i = t; i < 1024; i += 512) {
            int row = i >> 4, c = i & 15;
            *(uint4*)&w2T_s[row*136 + c*8] = s2[i];
        }
    }
    __syncthreads();

    const int w = t >> 6, lane = t & 63;
    const int ml = lane & 15, quad = lane >> 4;
    const int tile = blockIdx.x * 8 + w;
    if (tile >= NN / 16) return;
    const int e0 = tile * 16;
    unsigned short* st = stg[w];

    // ---- GEMM1: tt = h_attn @ WO
    const float4* ap = (const float4*)(h_attn + (size_t)(e0 + ml) * D);
    floatx4 acc1[4] = {};
#pragma unroll
    for (int kt = 0; kt < 2; kt++) {
        float4 f0 = ap[kt*8 + quad*2 + 0];
        float4 f1 = ap[kt*8 + quad*2 + 1];
        bf16x8 b;
        b[0] = (__bf16)f0.x; b[1] = (__bf16)f0.y; b[2] = (__bf16)f0.z; b[3] = (__bf16)f0.w;
        b[4] = (__bf16)f1.x; b[5] = (__bf16)f1.y; b[6] = (__bf16)f1.z; b[7] = (__bf16)f1.w;
#pragma unroll
        for (int mt = 0; mt < 4; mt++) {
            bf16x8 a = *(const bf16x8*)&woT_s[(mt*16 + ml)*72 + kt*32 + quad*8];
            acc1[mt] = __builtin_amdgcn_mfma_f32_16x16x32_bf16(a, b, acc1[mt], 0, 0, 0);
        }
    }
    const float4* hp  = (const float4*)(h_in + (size_t)(e0 + ml) * D);
    const float4* bo4 = (const float4*)bo;
    floatx4 tt[4];
#pragma unroll
    for (int mt = 0; mt < 4; mt++) {
        float4 hh = hp[mt*4 + quad];
        float4 bb = bo4[mt*4 + quad];
        tt[mt][0] = acc1[mt][0] + hh.x + bb.x;
        tt[mt][1] = acc1[mt][1] + hh.y + bb.y;
        tt[mt][2] = acc1[mt][2] + hh.z + bb.z;
        tt[mt][3] = acc1[mt][3] + hh.w + bb.w;
    }
    float s = 0.f;
#pragma unroll
    for (int mt = 0; mt < 4; mt++) s += tt[mt][0] + tt[mt][1] + tt[mt][2] + tt[mt][3];
    s += __shfl_xor(s, 16, 64); s += __shfl_xor(s, 32, 64);
    float mu = s * (1.f / 64.f);
    float v = 0.f;
#pragma unroll
    for (int mt = 0; mt < 4; mt++)
#pragma unroll
        for (int r = 0; r < 4; r++) { float c = tt[mt][r] - mu; v += c * c; }
    v += __shfl_xor(v, 16, 64); v += __shfl_xor(v, 32, 64);
    float rstd = rsqrtf(v * (1.f / 64.f) + 1e-5f);
    const float4* g1v  = (const float4*)g1;
    const float4* be1v = (const float4*)be1;
    floatx4 h1[4];
#pragma unroll
    for (int mt = 0; mt < 4; mt++) {
        float4 gg = g1v[mt*4 + quad];
        float4 bb = be1v[mt*4 + quad];
        h1[mt][0] = (tt[mt][0] - mu) * rstd * gg.x + bb.x;
        h1[mt][1] = (tt[mt][1] - mu) * rstd * gg.y + bb.y;
        h1[mt][2] = (tt[mt][2] - mu) * rstd * gg.z + bb.z;
        h1[mt][3] = (tt[mt][3] - mu) * rstd * gg.w + bb.w;
        *(ushort4*)&st[ml*136 + mt*16 + quad*4] =
            make_ushort4(f2bf(h1[mt][0]), f2bf(h1[mt][1]), f2bf(h1[mt][2]), f2bf(h1[mt][3]));
    }

    // ---- GEMM2: y = relu(h1 @ W1 + b1)
    bf16x8 bh[2];
#pragma unroll
    for (int kt = 0; kt < 2; kt++)
        bh[kt] = *(const bf16x8*)&st[ml*136 + kt*32 + quad*8];
    floatx4 acc2[8] = {};
#pragma unroll
    for (int kt = 0; kt < 2; kt++)
#pragma unroll
        for (int mt = 0; mt < 8; mt++) {
            bf16x8 a = *(const bf16x8*)&w1T_s[(mt*16 + ml)*72 + kt*32 + quad*8];
            acc2[mt] = __builtin_amdgcn_mfma_f32_16x16x32_bf16(a, bh[kt], acc2[mt], 0, 0, 0);
        }
    const float4* b1v = (const float4*)b1;
#pragma unroll
    for (int mt = 0; mt < 8; mt++) {
        float4 bb = b1v[mt*4 + quad];
        float y0 = fmaxf(acc2[mt][0] + bb.x, 0.f);
        float y1 = fmaxf(acc2[mt][1] + bb.y, 0.f);
        float y2 = fmaxf(acc2[mt][2] + bb.z, 0.f);
        float y3 = fmaxf(acc2[mt][3] + bb.w, 0.f);
        *(ushort4*)&st[ml*136 + mt*16 + quad*4] =
            make_ushort4(f2bf(y0), f2bf(y1), f2bf(y2), f2bf(y3));
    }

    // ---- GEMM3: z = y @ W2
    floatx4 acc3[4] = {};
#pragma unroll
    for (int kt = 0; kt < 4; kt++) {
        bf16x8 b = *(const bf16x8*)&st[ml*136 + kt*32 + quad*8];
#pragma unroll
        for (int mt = 0; mt < 4; mt++) {
            bf16x8 a = *(const bf16x8*)&w2T_s[(mt*16 + ml)*136 + kt*32 + quad*8];
            acc3[mt] = __builtin_amdgcn_mfma_f32_16x16x32_bf16(a, b, acc3[mt], 0, 0, 0);
        }
    }
    const float4* b2v = (const float4*)b2;
#pragma unroll
    for (int mt = 0; mt < 4; mt++) {
        float4 bb = b2v[mt*4 + quad];
        tt[mt][0] = acc3[mt][0] + bb.x + h1[mt][0];
        tt[mt][1] = acc3[mt][1] + bb.y + h1[mt][1];
        tt[mt][2] = acc3[mt][2] + bb.z + h1[mt][2];
        tt[mt][3] = acc3[mt][3] + bb.w + h1[mt][3];
    }
    s = 0.f;
#pragma unroll
    for (int mt = 0; mt < 4; mt++) s += tt[mt][0] + tt[mt][1] + tt[mt][2] + tt[mt][3];
    s += __shfl_xor(s, 16, 64); s += __shfl_xor(s, 32, 64);
    mu = s * (1.f / 64.f);
    v = 0.f;
#pragma unroll
    for (int mt = 0; mt < 4; mt++)
#pragma unroll
        for (int r = 0; r < 4; r++) { float c = tt[mt][r] - mu; v += c * c; }
    v += __shfl_xor(v, 16, 64); v += __shfl_xor(v, 32, 64);
    rstd = rsqrtf(v * (1.f / 64.f) + 1e-5f);
    const float4* g2v  = (const float4*)g2;
    const float4* be2v = (const float4*)be2;
    float4* outp = (float4*)(h_out + (size_t)(e0 + ml) * D);
#pragma unroll
    for (int mt = 0; mt < 4; mt++) {
        float4 gg = g2v[mt*4 + quad];
        float4 bb = be2v[mt*4 + quad];
        float4 o;
        o.x = (tt[mt][0] - mu) * rstd * gg.x + bb.x;
        o.y = (tt[mt][1] - mu) * rstd * gg.y + bb.y;
        o.z = (tt[mt][2] - mu) * rstd * gg.z + bb.z;
        o.w = (tt[mt][3] - mu) * rstd * gg.w + bb.w;
        outp[mt*4 + quad] = o;
    }
}

// ---------------- launch ----------------

extern "C" void kernel_launch(void* const* d_in, const int* in_sizes, int n_in,
                              void* d_out, int out_size, void* d_ws, size_t ws_size,
                              hipStream_t stream) {
    const float* x   = (const float*)d_in[0];
    const float* ea  = (const float*)d_in[1];
    const int*   ei  = (const int*)d_in[2];
    const float* WQ  = (const float*)d_in[3];
    const float* WK  = (const float*)d_in[4];
    const float* WE  = (const float*)d_in[5];
    const float* WV  = (const float*)d_in[6];
    const float* WO  = (const float*)d_in[7];
    const float* bO  = (const float*)d_in[8];
    const float* g1  = (const float*)d_in[9];
    const float* be1 = (const float*)d_in[10];
    const float* W1  = (const float*)d_in[11];
    const float* b1  = (const float*)d_in[12];
    const float* W2  = (const float*)d_in[13];
    const float* b2  = (const float*)d_in[14];
    const float* g2  = (const float*)d_in[15];
    const float* be2 = (const float*)d_in[16];
    float* out = (float*)d_out;

    char* wsb = (char*)d_ws;
    size_t off = 0;
    auto alloc = [&](size_t bytes) {
        void* p = wsb + off;
        off += (bytes + 255) & ~(size_t)255;
        return p;
    };
    float* Qh            = (float*)alloc((size_t)NN * D * 4);
    unsigned short* Kb   = (unsigned short*)alloc((size_t)NN * D * 2);
    unsigned short* Vb   = (unsigned short*)alloc((size_t)NN * D * 2);
    float* hbuf          = (float*)alloc((size_t)NN * D * 4);
    float* hattn         = (float*)alloc((size_t)NN * D * 4);
    unsigned short* Eh1  = (unsigned short*)alloc((size_t)NE * D * 2);
    float* scb           = (float*)alloc((size_t)NE * 4 * 4);
    int* row_off         = (int*)alloc((size_t)(NN + 1) * 4);
    int* cursor          = (int*)alloc((size_t)NN * 4);
    int* deg             = (int*)alloc((size_t)NN * 4);
    int* psum            = (int*)alloc((size_t)256 * 4);
    int* csr_src         = (int*)alloc((size_t)NE * 4);
    int* csr_dst         = (int*)alloc((size_t)NE * 4);
    int* eperm           = (int*)alloc((size_t)NE * 4);
    unsigned short* wqT  = (unsigned short*)alloc((size_t)2 * 4096 * 2);
    unsigned short* wkT  = (unsigned short*)alloc((size_t)2 * 4096 * 2);
    unsigned short* wvT  = (unsigned short*)alloc((size_t)2 * 4096 * 2);
    unsigned short* weT  = (unsigned short*)alloc((size_t)2 * 4096 * 2);
    unsigned short* woT  = (unsigned short*)alloc((size_t)2 * 4096 * 2);
    unsigned short* w1T  = (unsigned short*)alloc((size_t)2 * 8192 * 2);
    unsigned short* w2T  = (unsigned short*)alloc((size_t)2 * 8192 * 2);

    // CSR build + weight prep (once per call)
    hipMemsetAsync(deg, 0, (size_t)NN * 4, stream);
    k_deg<<<(NE + 255) / 256, 256, 0, stream>>>(ei, deg);
    k_scan1<<<NB, 256, 0, stream>>>(deg, psum);
    k_scan2<<<1, 256, 0, stream>>>(psum);
    k_scan3<<<NB, 256, 0, stream>>>(deg, psum, row_off, cursor);
    k_scatter<<<(NE + 255) / 256, 256, 0, stream>>>(ei, cursor, csr_src, csr_dst, eperm);
    k_prep<<<(2 * 36864 + 255) / 256, 256, 0, stream>>>(WQ, WK, WV, WE, WO, W1, W2,
            wqT, wkT, wvT, weT, woT, w1T, w2T);

    // layer 0 QKV must precede the Eh pass (layer-0 scores fused there)
    k_qkv_mfma<<<782, 256, 0, stream>>>(x, wqT, wkT, wvT, Qh, Kb, Vb);
    k_eh_score<<<1536, 256, 0, stream>>>(ea, weT, eperm, ei, Qh, Kb, scb, Eh1);

    // layer 0
    k_agg<<<(NN + 3) / 4, 256, 0, stream>>>(Vb, scb, row_off, csr_src, hattn);
    k_post_mfma<<<(NN / 16 + 7) / 8, 512, 0, stream>>>(x, hattn,
            woT, w1T, w2T, bO, g1, be1, b1, b2, g2, be2, hbuf);

    // layer 1
    k_qkv_mfma<<<782, 256, 0, stream>>>(hbuf, wqT + 4096, wkT + 4096,
                                        wvT + 4096, Qh, Kb, Vb);
    k_score1<<<1536, 256, 0, stream>>>(Eh1, Qh, Kb, csr_src, csr_dst, scb);
    k_agg<<<(NN + 3) / 4, 256, 0, stream>>>(Vb, scb, row_off, csr_src, hattn);
    k_post_mfma<<<(NN / 16 + 7) / 8, 512, 0, stream>>>(hbuf, hattn,
            woT + 4096, w1T + 8192, w2T + 8192,
            bO + 64, g1 + 64, be1 + 64, b1 + 128, b2 + 64,
            g2 + 64, be2 + 64, out);
}

// Round 3
// 605.824 us; speedup vs baseline: 1.0228x; 1.0228x over previous
//
#include <hip/hip_runtime.h>

#define NN 50000
#define NE 800000
#define D  64
#define NL 2
#define NB 196   // (NN + 255) / 256

typedef __bf16 bf16x8 __attribute__((ext_vector_type(8)));
typedef float  floatx4 __attribute__((ext_vector_type(4)));

static __device__ __forceinline__ float bf2f(unsigned short u) {
    return __uint_as_float(((unsigned)u) << 16);
}
static __device__ __forceinline__ unsigned short f2bf(float x) {
    unsigned u = __float_as_uint(x);
    u += 0x7fff + ((u >> 16) & 1);   // RNE
    return (unsigned short)(u >> 16);
}

// ---------------- CSR build (edge_index is identical for both layers) ----------------

__global__ void k_deg(const int* __restrict__ ei, int* __restrict__ deg) {
    int e = blockIdx.x * 256 + threadIdx.x;
    if (e < NE) atomicAdd(&deg[ei[NE + e]], 1);
}

__global__ __launch_bounds__(256) void k_scan1(const int* __restrict__ deg,
                                               int* __restrict__ psum) {
    __shared__ int red[4];
    int i = blockIdx.x * 256 + threadIdx.x;
    int v = (i < NN) ? deg[i] : 0;
#pragma unroll
    for (int m = 1; m < 64; m <<= 1) v += __shfl_xor(v, m, 64);
    if ((threadIdx.x & 63) == 0) red[threadIdx.x >> 6] = v;
    __syncthreads();
    if (threadIdx.x == 0) psum[blockIdx.x] = red[0] + red[1] + red[2] + red[3];
}

__global__ void k_scan2(int* __restrict__ psum) {
    __shared__ int buf[256];
    int t = threadIdx.x;
    int v = (t < NB) ? psum[t] : 0;
    buf[t] = v;
    __syncthreads();
    for (int o = 1; o < 256; o <<= 1) {
        int x = (t >= o) ? buf[t - o] : 0;
        __syncthreads();
        buf[t] += x;
        __syncthreads();
    }
    if (t < NB) psum[t] = buf[t] - v;   // exclusive
}

__global__ __launch_bounds__(256) void k_scan3(const int* __restrict__ deg,
                                               const int* __restrict__ psum,
                                               int* __restrict__ row_off,
                                               int* __restrict__ cursor) {
    __shared__ int buf[256];
    int t = threadIdx.x;
    int i = blockIdx.x * 256 + t;
    int v = (i < NN) ? deg[i] : 0;
    buf[t] = v;
    __syncthreads();
    for (int o = 1; o < 256; o <<= 1) {
        int x = (t >= o) ? buf[t - o] : 0;
        __syncthreads();
        buf[t] += x;
        __syncthreads();
    }
    if (i < NN) {
        int inc = buf[t] + psum[blockIdx.x];
        row_off[i + 1] = inc;
        cursor[i] = inc - v;
        if (i == 0) row_off[0] = 0;
    }
}

__global__ void k_scatter(const int* __restrict__ ei, int* __restrict__ cursor,
                          int* __restrict__ csr_src, int* __restrict__ csr_dst,
                          int* __restrict__ eperm) {
    int e = blockIdx.x * 256 + threadIdx.x;
    if (e < NE) {
        int dst = ei[NE + e];
        int pos = atomicAdd(&cursor[dst], 1);
        csr_src[pos] = ei[e];
        csr_dst[pos] = dst;
        eperm[e] = pos;
    }
}

// transpose all weights to bf16 m-major [m][k] once per call.
__global__ __launch_bounds__(256) void k_prep(
        const float* __restrict__ WQ, const float* __restrict__ WK,
        const float* __restrict__ WV, const float* __restrict__ WE,
        const float* __restrict__ WO, const float* __restrict__ W1,
        const float* __restrict__ W2,
        unsigned short* __restrict__ wqT, unsigned short* __restrict__ wkT,
        unsigned short* __restrict__ wvT, unsigned short* __restrict__ weT,
        unsigned short* __restrict__ woT, unsigned short* __restrict__ w1T,
        unsigned short* __restrict__ w2T) {
    int idx = blockIdx.x * 256 + threadIdx.x;
    if (idx >= 2 * 36864) return;
    int l = idx / 36864;
    int r = idx % 36864;
    if (r < 20480) {
        int which = r >> 12, rr = r & 4095;
        int m = rr >> 6, k = rr & 63;
        const float* src = (which == 0 ? WQ : which == 1 ? WK : which == 2 ? WV :
                            which == 3 ? WE : WO);
        unsigned short* dst = (which == 0 ? wqT : which == 1 ? wkT : which == 2 ? wvT :
                               which == 3 ? weT : woT);
        dst[l * 4096 + rr] = f2bf(src[l * 4096 + k * 64 + m]);
    } else if (r < 28672) {
        int r2 = r - 20480;
        int m = r2 >> 6, k = r2 & 63;
        w1T[l * 8192 + r2] = f2bf(W1[l * 8192 + k * 128 + m]);
    } else {
        int r3 = r - 28672;
        int m = r3 >> 7, k = r3 & 127;
        w2T[l * 8192 + r3] = f2bf(W2[l * 8192 + k * 64 + m]);
    }
}

// ---------------- kernels ----------------

// QKV via MFMA: one 16-node tile per wave. Q/K/V all bf16 via LDS transpose.
__global__ __launch_bounds__(256) void k_qkv_mfma(const float* __restrict__ h,
        const unsigned short* __restrict__ wqT, const unsigned short* __restrict__ wkT,
        const unsigned short* __restrict__ wvT,
        unsigned short* __restrict__ Qb, unsigned short* __restrict__ Kb,
        unsigned short* __restrict__ Vb) {
    __shared__ unsigned short st[4][16 * 72];
    const int lane = threadIdx.x & 63;
    const int w    = threadIdx.x >> 6;
    const int ml   = lane & 15;
    const int quad = lane >> 4;

    bf16x8 aq[2][4], ak[2][4], av[2][4];
#pragma unroll
    for (int kt = 0; kt < 2; kt++)
#pragma unroll
        for (int mt = 0; mt < 4; mt++) {
            int o = (mt*16 + ml)*64 + kt*32 + quad*8;
            aq[kt][mt] = *(const bf16x8*)&wqT[o];
            ak[kt][mt] = *(const bf16x8*)&wkT[o];
            av[kt][mt] = *(const bf16x8*)&wvT[o];
        }

    const int wave = blockIdx.x * 4 + w;
    const int nw   = gridDim.x * 4;
    const int el = lane >> 2, c = lane & 3;
    for (int tile = wave; tile < NN / 16; tile += nw) {
        const int e0 = tile * 16;
        const float4* ar = (const float4*)(h + (size_t)(e0 + ml) * D);
        bf16x8 b[2];
#pragma unroll
        for (int kt = 0; kt < 2; kt++) {
            float4 f0 = ar[kt*8 + quad*2 + 0];
            float4 f1 = ar[kt*8 + quad*2 + 1];
            b[kt][0] = (__bf16)f0.x; b[kt][1] = (__bf16)f0.y;
            b[kt][2] = (__bf16)f0.z; b[kt][3] = (__bf16)f0.w;
            b[kt][4] = (__bf16)f1.x; b[kt][5] = (__bf16)f1.y;
            b[kt][6] = (__bf16)f1.z; b[kt][7] = (__bf16)f1.w;
        }
        floatx4 accq[4] = {}, acck[4] = {}, accv[4] = {};
#pragma unroll
        for (int kt = 0; kt < 2; kt++)
#pragma unroll
            for (int mt = 0; mt < 4; mt++) {
                accq[mt] = __builtin_amdgcn_mfma_f32_16x16x32_bf16(aq[kt][mt], b[kt], accq[mt], 0, 0, 0);
                acck[mt] = __builtin_amdgcn_mfma_f32_16x16x32_bf16(ak[kt][mt], b[kt], acck[mt], 0, 0, 0);
                accv[mt] = __builtin_amdgcn_mfma_f32_16x16x32_bf16(av[kt][mt], b[kt], accv[mt], 0, 0, 0);
            }
#pragma unroll
        for (int mt = 0; mt < 4; mt++)
            *(ushort4*)&st[w][ml*72 + mt*16 + quad*4] =
                make_ushort4(f2bf(accq[mt][0]), f2bf(accq[mt][1]),
                             f2bf(accq[mt][2]), f2bf(accq[mt][3]));
        {
            uint4 r0 = *(const uint4*)&st[w][el*72 + c*16 + 0];
            uint4 r1 = *(const uint4*)&st[w][el*72 + c*16 + 8];
            uint4* gp = (uint4*)(Qb + (size_t)(e0 + el) * D + c*16);
            gp[0] = r0; gp[1] = r1;
        }
#pragma unroll
        for (int mt = 0; mt < 4; mt++)
            *(ushort4*)&st[w][ml*72 + mt*16 + quad*4] =
                make_ushort4(f2bf(acck[mt][0]), f2bf(acck[mt][1]),
                             f2bf(acck[mt][2]), f2bf(acck[mt][3]));
        {
            uint4 r0 = *(const uint4*)&st[w][el*72 + c*16 + 0];
            uint4 r1 = *(const uint4*)&st[w][el*72 + c*16 + 8];
            uint4* gp = (uint4*)(Kb + (size_t)(e0 + el) * D + c*16);
            gp[0] = r0; gp[1] = r1;
        }
#pragma unroll
        for (int mt = 0; mt < 4; mt++)
            *(ushort4*)&st[w][ml*72 + mt*16 + quad*4] =
                make_ushort4(f2bf(accv[mt][0]), f2bf(accv[mt][1]),
                             f2bf(accv[mt][2]), f2bf(accv[mt][3]));
        {
            uint4 r0 = *(const uint4*)&st[w][el*72 + c*16 + 0];
            uint4 r1 = *(const uint4*)&st[w][el*72 + c*16 + 8];
            uint4* gp = (uint4*)(Vb + (size_t)(e0 + el) * D + c*16);
            gp[0] = r0; gp[1] = r1;
        }
    }
}

// Eh pass: layer-0 scores in-register (Eh0 never materialized), Eh1 to memory
// (CSR order). Weights in LDS (padded 72-short rows, conflict-free), Q/K gathers
// issued at loop top, next-tile scalars prefetched.
__global__ __launch_bounds__(256) void k_eh_score(const float* __restrict__ ea,
        const unsigned short* __restrict__ weT, const int* __restrict__ eperm,
        const int* __restrict__ ei, const unsigned short* __restrict__ Qb,
        const unsigned short* __restrict__ Kb,
        float* __restrict__ scb, unsigned short* __restrict__ Eh1) {
    __shared__ unsigned short wsm[2 * 4608];     // [l][64 rows][72 shorts]
    __shared__ unsigned short st[4][16 * 72];
    const int t = threadIdx.x;
    for (int i = t; i < 1024; i += 256) {        // 2 layers * 512 chunks of 16B
        int l = i >> 9, r = i & 511;
        *(uint4*)&wsm[l*4608 + (r >> 3)*72 + (r & 7)*8] = ((const uint4*)weT)[i];
    }
    __syncthreads();

    const int lane = t & 63;
    const int w    = t >> 6;
    const int ml   = lane & 15;
    const int quad = lane >> 4;
    const int el = lane >> 2, c = lane & 3;
    const int wave = blockIdx.x * 4 + w;
    const int nw   = gridDim.x * 4;
    const int NT   = NE / 16;

    int tile = wave;
    if (tile >= NT) return;
    int srcn = ei[tile*16 + ml];
    int dstn = ei[NE + tile*16 + ml];
    int posm = eperm[tile*16 + ml];
    int pose = eperm[tile*16 + el];

    for (; tile < NT; tile += nw) {
        // ea stream (16 rows x 256B per wave, coalesced)
        const float4* ar = (const float4*)(ea + (size_t)(tile*16 + ml) * D);
        float4 f00 = ar[quad*2 + 0];
        float4 f01 = ar[quad*2 + 1];
        float4 f10 = ar[8 + quad*2 + 0];
        float4 f11 = ar[8 + quad*2 + 1];
        // issue score gathers early (bf16 Q and K): dims mt*16 + quad*4
        ushort4 qg[4], kg[4];
#pragma unroll
        for (int mt = 0; mt < 4; mt++) {
            qg[mt] = *(const ushort4*)(Qb + (size_t)dstn * D + mt*16 + quad*4);
            kg[mt] = *(const ushort4*)(Kb + (size_t)srcn * D + mt*16 + quad*4);
        }
        // prefetch next tile's scalars
        int nxt = tile + nw;
        int nsrc = srcn, ndst = dstn, nposm = posm, npose = pose;
        if (nxt < NT) {
            nsrc  = ei[nxt*16 + ml];
            ndst  = ei[NE + nxt*16 + ml];
            nposm = eperm[nxt*16 + ml];
            npose = eperm[nxt*16 + el];
        }
        bf16x8 b[2];
        b[0][0] = (__bf16)f00.x; b[0][1] = (__bf16)f00.y;
        b[0][2] = (__bf16)f00.z; b[0][3] = (__bf16)f00.w;
        b[0][4] = (__bf16)f01.x; b[0][5] = (__bf16)f01.y;
        b[0][6] = (__bf16)f01.z; b[0][7] = (__bf16)f01.w;
        b[1][0] = (__bf16)f10.x; b[1][1] = (__bf16)f10.y;
        b[1][2] = (__bf16)f10.z; b[1][3] = (__bf16)f10.w;
        b[1][4] = (__bf16)f11.x; b[1][5] = (__bf16)f11.y;
        b[1][6] = (__bf16)f11.z; b[1][7] = (__bf16)f11.w;

        // ---- layer 1 first (covers gather latency): Eh1 materialization
        {
            floatx4 acc[4] = {};
#pragma unroll
            for (int kt = 0; kt < 2; kt++)
#pragma unroll
                for (int mt = 0; mt < 4; mt++) {
                    bf16x8 a = *(const bf16x8*)&wsm[4608 + (mt*16 + ml)*72 + kt*32 + quad*8];
                    acc[mt] = __builtin_amdgcn_mfma_f32_16x16x32_bf16(a, b[kt], acc[mt], 0, 0, 0);
                }
#pragma unroll
            for (int mt = 0; mt < 4; mt++)
                *(ushort4*)&st[w][ml*72 + mt*16 + quad*4] =
                    make_ushort4(f2bf(acc[mt][0]), f2bf(acc[mt][1]),
                                 f2bf(acc[mt][2]), f2bf(acc[mt][3]));
            uint4 r0 = *(const uint4*)&st[w][el*72 + c*16 + 0];
            uint4 r1 = *(const uint4*)&st[w][el*72 + c*16 + 8];
            uint4* gp = (uint4*)(Eh1 + (size_t)pose * D + c*16);
            gp[0] = r0;
            gp[1] = r1;
        }
        // ---- layer 0: score in-register
        {
            floatx4 acc[4] = {};
#pragma unroll
            for (int kt = 0; kt < 2; kt++)
#pragma unroll
                for (int mt = 0; mt < 4; mt++) {
                    bf16x8 a = *(const bf16x8*)&wsm[(mt*16 + ml)*72 + kt*32 + quad*8];
                    acc[mt] = __builtin_amdgcn_mfma_f32_16x16x32_bf16(a, b[kt], acc[mt], 0, 0, 0);
                }
            float scq[4];
#pragma unroll
            for (int mt = 0; mt < 4; mt++) {
                float p = acc[mt][0] * bf2f(qg[mt].x) * bf2f(kg[mt].x)
                        + acc[mt][1] * bf2f(qg[mt].y) * bf2f(kg[mt].y)
                        + acc[mt][2] * bf2f(qg[mt].z) * bf2f(kg[mt].z)
                        + acc[mt][3] * bf2f(qg[mt].w) * bf2f(kg[mt].w);
                p += __shfl_xor(p, 16, 64);
                p += __shfl_xor(p, 32, 64);
                scq[mt] = __expf(fminf(5.f, fmaxf(-5.f, p * 0.25f)));
            }
            if (quad == 0)
                *(float4*)(scb + (size_t)posm * 4) =
                    make_float4(scq[0], scq[1], scq[2], scq[3]);
        }
        srcn = nsrc; dstn = ndst; posm = nposm; pose = npose;
    }
}

// layer-1 edge scores: lane = (edge ml, head quad), 16 dims in-lane, zero
// shuffles. Software-pipelined: Eh rows + indices prefetched one tile ahead.
__global__ __launch_bounds__(256) void k_score1(
        const unsigned short* __restrict__ Eh1,
        const unsigned short* __restrict__ Qb, const unsigned short* __restrict__ Kb,
        const int* __restrict__ csr_src, const int* __restrict__ csr_dst,
        float* __restrict__ scb) {
    const int lane = threadIdx.x & 63;
    const int w    = threadIdx.x >> 6;
    const int ml   = lane & 15;
    const int quad = lane >> 4;      // head index
    const int wave = blockIdx.x * 4 + w;
    const int nw   = gridDim.x * 4;
    const int NT   = NE / 16;
    int tile = wave;
    if (tile >= NT) return;
    int p0 = tile*16 + ml;
    int src = csr_src[p0], dst = csr_dst[p0];
    bf16x8 e0 = *(const bf16x8*)(Eh1 + (size_t)p0 * D + quad*16);
    bf16x8 e1 = *(const bf16x8*)(Eh1 + (size_t)p0 * D + quad*16 + 8);
    for (; tile < NT; tile += nw) {
        bf16x8 k0 = *(const bf16x8*)(Kb + (size_t)src * D + quad*16);
        bf16x8 k1 = *(const bf16x8*)(Kb + (size_t)src * D + quad*16 + 8);
        bf16x8 q0 = *(const bf16x8*)(Qb + (size_t)dst * D + quad*16);
        bf16x8 q1 = *(const bf16x8*)(Qb + (size_t)dst * D + quad*16 + 8);
        int nxt = tile + nw;
        int nsrc = src, ndst = dst;
        bf16x8 ne0 = e0, ne1 = e1;
        if (nxt < NT) {
            int pn = nxt*16 + ml;
            nsrc = csr_src[pn]; ndst = csr_dst[pn];
            ne0 = *(const bf16x8*)(Eh1 + (size_t)pn * D + quad*16);
            ne1 = *(const bf16x8*)(Eh1 + (size_t)pn * D + quad*16 + 8);
        }
        float s = 0.f;
#pragma unroll
        for (int i = 0; i < 8; i++) s += (float)e0[i] * (float)q0[i] * (float)k0[i];
#pragma unroll
        for (int i = 0; i < 8; i++) s += (float)e1[i] * (float)q1[i] * (float)k1[i];
        scb[(size_t)(tile*16 + ml) * 4 + quad] = __expf(fminf(5.f, fmaxf(-5.f, s * 0.25f)));
        src = nsrc; dst = ndst; e0 = ne0; e1 = ne1;
    }
}

// attention aggregation: one wave per node; only score read + V gather per edge.
__global__ __launch_bounds__(256) void k_agg(
        const unsigned short* __restrict__ Vb, const float* __restrict__ scb,
        const int* __restrict__ row_off, const int* __restrict__ csr_src,
        float* __restrict__ h_attn) {
    const int node = blockIdx.x * 4 + (threadIdx.x >> 6);
    if (node >= NN) return;
    const int lane  = threadIdx.x & 63;
    const int eslot = lane >> 4;
    const int ml    = lane & 15;
    const int hsel  = ml >> 2;
    const int beg = row_off[node], end = row_off[node + 1];
    float4 acc = make_float4(0.f, 0.f, 0.f, 0.f);
    float z = 0.f;

    for (int cbeg = beg; cbeg < end; cbeg += 64) {
        const int cnt = min(64, end - cbeg);
        int myidx = cbeg + lane;
        int mysrc = (myidx < end) ? csr_src[myidx] : 0;

        for (int base = 0; base < cnt; base += 16) {
            int  jj[4];
            int  s[4];
            bool act[4];
#pragma unroll
            for (int u = 0; u < 4; u++) {
                int j = base + eslot + 4 * u;
                act[u] = j < cnt;
                jj[u]  = act[u] ? j : 0;
                s[u]   = __shfl(mysrc, jj[u], 64);
            }
            ushort4 vb[4];
            float   sv[4];
#pragma unroll
            for (int u = 0; u < 4; u++) {
                vb[u] = *(const ushort4*)(Vb + (size_t)s[u] * D + ml * 4);
                sv[u] = scb[(size_t)(cbeg + jj[u]) * 4 + hsel];
            }
#pragma unroll
            for (int u = 0; u < 4; u++) {
                float sc = act[u] ? sv[u] : 0.f;
                acc.x += sc * bf2f(vb[u].x);
                acc.y += sc * bf2f(vb[u].y);
                acc.z += sc * bf2f(vb[u].z);
                acc.w += sc * bf2f(vb[u].w);
                z += sc;
            }
        }
    }
#pragma unroll
    for (int m = 16; m <= 32; m <<= 1) {
        acc.x += __shfl_xor(acc.x, m, 64);
        acc.y += __shfl_xor(acc.y, m, 64);
        acc.z += __shfl_xor(acc.z, m, 64);
        acc.w += __shfl_xor(acc.w, m, 64);
        z     += __shfl_xor(z, m, 64);
    }
    if (eslot == 0) {
        float inv = 1.f / (z + 1e-6f);
        ((float4*)(h_attn + (size_t)node * D))[ml] =
            make_float4(acc.x * inv, acc.y * inv, acc.z * inv, acc.w * inv);
    }
}

// MFMA-based fused post block: one 16-node tile per wave.
__global__ __launch_bounds__(512) void k_post_mfma(const float* __restrict__ h_in,
        const float* __restrict__ h_attn,
        const unsigned short* __restrict__ woT_g,
        const unsigned short* __restrict__ w1T_g,
        const unsigned short* __restrict__ w2T_g,
        const float* __restrict__ bo,
        const float* __restrict__ g1, const float* __restrict__ be1,
        const float* __restrict__ b1, const float* __restrict__ b2,
        const float* __restrict__ g2, const float* __restrict__ be2,
        float* __restrict__ h_out) {
    __shared__ unsigned short woT_s[64 * 72];
    __shared__ unsigned short w1T_s[128 * 72];
    __shared__ unsigned short w2T_s[64 * 136];
    __shared__ unsigned short stg[8][16 * 136];

    const int t = threadIdx.x;
    {
        const uint4* s0 = (const uint4*)woT_g;
        { int i = t; if (i < 512) { int row = i >> 3, c = i & 7;
              *(uint4*)&woT_s[row*72 + c*8] = s0[i]; } }
        const uint4* s1 = (const uint4*)w1T_g;
        for (int i = t; i < 1024; i += 512) {
            int row = i >> 3, c = i & 7;
            *(uint4*)&w1T_s[row*72 + c*8] = s1[i];
        }
        const uint4* s2 = (const uint4*)w2T_g;
        for (int i = t; i < 1024; i += 512) {
            int row = i >> 4, c = i & 15;
            *(uint4*)&w2T_s[row*136 + c*8] = s2[i];
        }
    }
    __syncthreads();

    const int w = t >> 6, lane = t & 63;
    const int ml = lane & 15, quad = lane >> 4;
    const int tile = blockIdx.x * 8 + w;
    if (tile >= NN / 16) return;
    const int e0 = tile * 16;
    unsigned short* st = stg[w];

    // ---- GEMM1: tt = h_attn @ WO
    const float4* ap = (const float4*)(h_attn + (size_t)(e0 + ml) * D);
    floatx4 acc1[4] = {};
#pragma unroll
    for (int kt = 0; kt < 2; kt++) {
        float4 f0 = ap[kt*8 + quad*2 + 0];
        float4 f1 = ap[kt*8 + quad*2 + 1];
        bf16x8 b;
        b[0] = (__bf16)f0.x; b[1] = (__bf16)f0.y; b[2] = (__bf16)f0.z; b[3] = (__bf16)f0.w;
        b[4] = (__bf16)f1.x; b[5] = (__bf16)f1.y; b[6] = (__bf16)f1.z; b[7] = (__bf16)f1.w;
#pragma unroll
        for (int mt = 0; mt < 4; mt++) {
            bf16x8 a = *(const bf16x8*)&woT_s[(mt*16 + ml)*72 + kt*32 + quad*8];
            acc1[mt] = __builtin_amdgcn_mfma_f32_16x16x32_bf16(a, b, acc1[mt], 0, 0, 0);
        }
    }
    const float4* hp  = (const float4*)(h_in + (size_t)(e0 + ml) * D);
    const float4* bo4 = (const float4*)bo;
    floatx4 tt[4];
#pragma unroll
    for (int mt = 0; mt < 4; mt++) {
        float4 hh = hp[mt*4 + quad];
        float4 bb = bo4[mt*4 + quad];
        tt[mt][0] = acc1[mt][0] + hh.x + bb.x;
        tt[mt][1] = acc1[mt][1] + hh.y + bb.y;
        tt[mt][2] = acc1[mt][2] + hh.z + bb.z;
        tt[mt][3] = acc1[mt][3] + hh.w + bb.w;
    }
    float s = 0.f;
#pragma unroll
    for (int mt = 0; mt < 4; mt++) s += tt[mt][0] + tt[mt][1] + tt[mt][2] + tt[mt][3];
    s += __shfl_xor(s, 16, 64); s += __shfl_xor(s, 32, 64);
    float mu = s * (1.f / 64.f);
    float v = 0.f;
#pragma unroll
    for (int mt = 0; mt < 4; mt++)
#pragma unroll
        for (int r = 0; r < 4; r++) { float c = tt[mt][r] - mu; v += c * c; }
    v += __shfl_xor(v, 16, 64); v += __shfl_xor(v, 32, 64);
    float rstd = rsqrtf(v * (1.f / 64.f) + 1e-5f);
    const float4* g1v  = (const float4*)g1;
    const float4* be1v = (const float4*)be1;
    floatx4 h1[4];
#pragma unroll
    for (int mt = 0; mt < 4; mt++) {
        float4 gg = g1v[mt*4 + quad];
        float4 bb = be1v[mt*4 + quad];
        h1[mt][0] = (tt[mt][0] - mu) * rstd * gg.x + bb.x;
        h1[mt][1] = (tt[mt][1] - mu) * rstd * gg.y + bb.y;
        h1[mt][2] = (tt[mt][2] - mu) * rstd * gg.z + bb.z;
        h1[mt][3] = (tt[mt][3] - mu) * rstd * gg.w + bb.w;
        *(ushort4*)&st[ml*136 + mt*16 + quad*4] =
            make_ushort4(f2bf(h1[mt][0]), f2bf(h1[mt][1]), f2bf(h1[mt][2]), f2bf(h1[mt][3]));
    }

    // ---- GEMM2: y = relu(h1 @ W1 + b1)
    bf16x8 bh[2];
#pragma unroll
    for (int kt = 0; kt < 2; kt++)
        bh[kt] = *(const bf16x8*)&st[ml*136 + kt*32 + quad*8];
    floatx4 acc2[8] = {};
#pragma unroll
    for (int kt = 0; kt < 2; kt++)
#pragma unroll
        for (int mt = 0; mt < 8; mt++) {
            bf16x8 a = *(const bf16x8*)&w1T_s[(mt*16 + ml)*72 + kt*32 + quad*8];
            acc2[mt] = __builtin_amdgcn_mfma_f32_16x16x32_bf16(a, bh[kt], acc2[mt], 0, 0, 0);
        }
    const float4* b1v = (const float4*)b1;
#pragma unroll
    for (int mt = 0; mt < 8; mt++) {
        float4 bb = b1v[mt*4 + quad];
        float y0 = fmaxf(acc2[mt][0] + bb.x, 0.f);
        float y1 = fmaxf(acc2[mt][1] + bb.y, 0.f);
        float y2 = fmaxf(acc2[mt][2] + bb.z, 0.f);
        float y3 = fmaxf(acc2[mt][3] + bb.w, 0.f);
        *(ushort4*)&st[ml*136 + mt*16 + quad*4] =
            make_ushort4(f2bf(y0), f2bf(y1), f2bf(y2), f2bf(y3));
    }

    // ---- GEMM3: z = y @ W2
    floatx4 acc3[4] = {};
#pragma unroll
    for (int kt = 0; kt < 4; kt++) {
        bf16x8 b = *(const bf16x8*)&st[ml*136 + kt*32 + quad*8];
#pragma unroll
        for (int mt = 0; mt < 4; mt++) {
            bf16x8 a = *(const bf16x8*)&w2T_s[(mt*16 + ml)*136 + kt*32 + quad*8];
            acc3[mt] = __builtin_amdgcn_mfma_f32_16x16x32_bf16(a, b, acc3[mt], 0, 0, 0);
        }
    }
    const float4* b2v = (const float4*)b2;
#pragma unroll
    for (int mt = 0; mt < 4; mt++) {
        float4 bb = b2v[mt*4 + quad];
        tt[mt][0] = acc3[mt][0] + bb.x + h1[mt][0];
        tt[mt][1] = acc3[mt][1] + bb.y + h1[mt][1];
        tt[mt][2] = acc3[mt][2] + bb.z + h1[mt][2];
        tt[mt][3] = acc3[mt][3] + bb.w + h1[mt][3];
    }
    s = 0.f;
#pragma unroll
    for (int mt = 0; mt < 4; mt++) s += tt[mt][0] + tt[mt][1] + tt[mt][2] + tt[mt][3];
    s += __shfl_xor(s, 16, 64); s += __shfl_xor(s, 32, 64);
    mu = s * (1.f / 64.f);
    v = 0.f;
#pragma unroll
    for (int mt = 0; mt < 4; mt++)
#pragma unroll
        for (int r = 0; r < 4; r++) { float c = tt[mt][r] - mu; v += c * c; }
    v += __shfl_xor(v, 16, 64); v += __shfl_xor(v, 32, 64);
    rstd = rsqrtf(v * (1.f / 64.f) + 1e-5f);
    const float4* g2v  = (const float4*)g2;
    const float4* be2v = (const float4*)be2;
    float4* outp = (float4*)(h_out + (size_t)(e0 + ml) * D);
#pragma unroll
    for (int mt = 0; mt < 4; mt++) {
        float4 gg = g2v[mt*4 + quad];
        float4 bb = be2v[mt*4 + quad];
        float4 o;
        o.x = (tt[mt][0] - mu) * rstd * gg.x + bb.x;
        o.y = (tt[mt][1] - mu) * rstd * gg.y + bb.y;
        o.z = (tt[mt][2] - mu) * rstd * gg.z + bb.z;
        o.w = (tt[mt][3] - mu) * rstd * gg.w + bb.w;
        outp[mt*4 + quad] = o;
    }
}

// ---------------- launch ----------------

extern "C" void kernel_launch(void* const* d_in, const int* in_sizes, int n_in,
                              void* d_out, int out_size, void* d_ws, size_t ws_size,
                              hipStream_t stream) {
    const float* x   = (const float*)d_in[0];
    const float* ea  = (const float*)d_in[1];
    const int*   ei  = (const int*)d_in[2];
    const float* WQ  = (const float*)d_in[3];
    const float* WK  = (const float*)d_in[4];
    const float* WE  = (const float*)d_in[5];
    const float* WV  = (const float*)d_in[6];
    const float* WO  = (const float*)d_in[7];
    const float* bO  = (const float*)d_in[8];
    const float* g1  = (const float*)d_in[9];
    const float* be1 = (const float*)d_in[10];
    const float* W1  = (const float*)d_in[11];
    const float* b1  = (const float*)d_in[12];
    const float* W2  = (const float*)d_in[13];
    const float* b2  = (const float*)d_in[14];
    const float* g2  = (const float*)d_in[15];
    const float* be2 = (const float*)d_in[16];
    float* out = (float*)d_out;

    char* wsb = (char*)d_ws;
    size_t off = 0;
    auto alloc = [&](size_t bytes) {
        void* p = wsb + off;
        off += (bytes + 255) & ~(size_t)255;
        return p;
    };
    unsigned short* Qb   = (unsigned short*)alloc((size_t)NN * D * 2);
    unsigned short* Kb   = (unsigned short*)alloc((size_t)NN * D * 2);
    unsigned short* Vb   = (unsigned short*)alloc((size_t)NN * D * 2);
    float* hbuf          = (float*)alloc((size_t)NN * D * 4);
    float* hattn         = (float*)alloc((size_t)NN * D * 4);
    unsigned short* Eh1  = (unsigned short*)alloc((size_t)NE * D * 2);
    float* scb           = (float*)alloc((size_t)NE * 4 * 4);
    int* row_off         = (int*)alloc((size_t)(NN + 1) * 4);
    int* cursor          = (int*)alloc((size_t)NN * 4);
    int* deg             = (int*)alloc((size_t)NN * 4);
    int* psum            = (int*)alloc((size_t)256 * 4);
    int* csr_src         = (int*)alloc((size_t)NE * 4);
    int* csr_dst         = (int*)alloc((size_t)NE * 4);
    int* eperm           = (int*)alloc((size_t)NE * 4);
    unsigned short* wqT  = (unsigned short*)alloc((size_t)2 * 4096 * 2);
    unsigned short* wkT  = (unsigned short*)alloc((size_t)2 * 4096 * 2);
    unsigned short* wvT  = (unsigned short*)alloc((size_t)2 * 4096 * 2);
    unsigned short* weT  = (unsigned short*)alloc((size_t)2 * 4096 * 2);
    unsigned short* woT  = (unsigned short*)alloc((size_t)2 * 4096 * 2);
    unsigned short* w1T  = (unsigned short*)alloc((size_t)2 * 8192 * 2);
    unsigned short* w2T  = (unsigned short*)alloc((size_t)2 * 8192 * 2);

    // CSR build + weight prep (once per call)
    hipMemsetAsync(deg, 0, (size_t)NN * 4, stream);
    k_deg<<<(NE + 255) / 256, 256, 0, stream>>>(ei, deg);
    k_scan1<<<NB, 256, 0, stream>>>(deg, psum);
    k_scan2<<<1, 256, 0, stream>>>(psum);
    k_scan3<<<NB, 256, 0, stream>>>(deg, psum, row_off, cursor);
    k_scatter<<<(NE + 255) / 256, 256, 0, stream>>>(ei, cursor, csr_src, csr_dst, eperm);
    k_prep<<<(2 * 36864 + 255) / 256, 256, 0, stream>>>(WQ, WK, WV, WE, WO, W1, W2,
            wqT, wkT, wvT, weT, woT, w1T, w2T);

    // layer 0 QKV must precede the Eh pass (layer-0 scores fused there)
    k_qkv_mfma<<<782, 256, 0, stream>>>(x, wqT, wkT, wvT, Qb, Kb, Vb);
    k_eh_score<<<1280, 256, 0, stream>>>(ea, weT, eperm, ei, Qb, Kb, scb, Eh1);

    // layer 0
    k_agg<<<(NN + 3) / 4, 256, 0, stream>>>(Vb, scb, row_off, csr_src, hattn);
    k_post_mfma<<<(NN / 16 + 7) / 8, 512, 0, stream>>>(x, hattn,
            woT, w1T, w2T, bO, g1, be1, b1, b2, g2, be2, hbuf);

    // layer 1
    k_qkv_mfma<<<782, 256, 0, stream>>>(hbuf, wqT + 4096, wkT + 4096,
                                        wvT + 4096, Qb, Kb, Vb);
    k_score1<<<1536, 256, 0, stream>>>(Eh1, Qb, Kb, csr_src, csr_dst, scb);
    k_agg<<<(NN + 3) / 4, 256, 0, stream>>>(Vb, scb, row_off, csr_src, hattn);
    k_post_mfma<<<(NN / 16 + 7) / 8, 512, 0, stream>>>(hbuf, hattn,
            woT + 4096, w1T + 8192, w2T + 8192,
            bO + 64, g1 + 64, be1 + 64, b1 + 128, b2 + 64,
            g2 + 64, be2 + 64, out);
}